// Round 1
// baseline (98.828 us; speedup 1.0000x reference)
//
#include <hip/hip_runtime.h>

#define BB 16384
#define LL 256
#define HH 16
#define RS 16   // samples per block; grid = BB/RS = 1024 blocks = 4 blocks/CU

static __device__ __forceinline__ float fast_exp2(float x) { return __builtin_amdgcn_exp2f(x); }
static __device__ __forceinline__ float fast_log2(float x) { return __builtin_amdgcn_logf(x); }

// Single fused exact kernel. One lane per latent (blockDim.x == LL == 256),
// RS samples per block. Params live in registers, pre-scaled to base-2 domain:
//   softplus(x)*log2e = max(x2,0) + log2(1 + 2^-|x2|),  x2 = x*log2e
//   sigmoid(a)        = 1 / (1 + 2^-(a*log2e))
// Exact for all y (exp2 underflow -> log2(1) = 0 -> sp = max(x2,0), correct).
// No d_ws usage, no LUT, no second launch.
__global__ __launch_bounds__(256) void fused_mlp(
    const float* __restrict__ y, float* __restrict__ out,
    const float* __restrict__ W1, const float* __restrict__ b1,
    const float* __restrict__ W2, const float* __restrict__ b2)
{
    const float LOG2E = 1.4426950408889634f;
    const int l = threadIdx.x;                 // latent index, 0..255

    // Preload per-latent params into registers (48 f32), vectorized 16B loads.
    // Wave reads 4 KB contiguous -> fully coalesced; params are L1/L2-hot.
    float w1[HH], c1[HH], w2[HH];
    const float4* __restrict__ W1v = reinterpret_cast<const float4*>(W1 + l * HH);
    const float4* __restrict__ b1v = reinterpret_cast<const float4*>(b1 + l * HH);
    const float4* __restrict__ W2v = reinterpret_cast<const float4*>(W2 + l * HH);
    #pragma unroll
    for (int q = 0; q < HH / 4; ++q) {
        float4 a = W1v[q], c = b1v[q], d = W2v[q];
        w1[q * 4 + 0] = a.x * LOG2E; w1[q * 4 + 1] = a.y * LOG2E;
        w1[q * 4 + 2] = a.z * LOG2E; w1[q * 4 + 3] = a.w * LOG2E;
        c1[q * 4 + 0] = c.x * LOG2E; c1[q * 4 + 1] = c.y * LOG2E;
        c1[q * 4 + 2] = c.z * LOG2E; c1[q * 4 + 3] = c.w * LOG2E;
        w2[q * 4 + 0] = d.x; w2[q * 4 + 1] = d.y;
        w2[q * 4 + 2] = d.z; w2[q * 4 + 3] = d.w;
    }
    const float a2 = b2[l] * LOG2E;

    const int b0 = blockIdx.x * RS;
    #pragma unroll 2                           // mild ILP: overlap y-load with trans chain
    for (int r = 0; r < RS; ++r) {
        float yv = y[(b0 + r) * LL + l];       // wave reads 256B contiguous: coalesced
        float acc = a2;
        #pragma unroll
        for (int h = 0; h < HH; ++h) {
            float x2 = fmaf(yv, w1[h], c1[h]);
            float e  = fast_exp2(-fabsf(x2));              // -abs() folds into input modifier
            float sp = fmaxf(x2, 0.0f) + fast_log2(1.0f + e);
            acc = fmaf(sp, w2[h], acc);
        }
        out[(b0 + r) * LL + l] =
            __builtin_amdgcn_rcpf(1.0f + fast_exp2(-acc)); // coalesced store
    }
}

extern "C" void kernel_launch(void* const* d_in, const int* in_sizes, int n_in,
                              void* d_out, int out_size, void* d_ws, size_t ws_size,
                              hipStream_t stream) {
    // inputs: 0=t, 1=y [B,L], 2=W1 [L,H], 3=b1 [L,H], 4=W2 [L,H], 5=b2 [L], 6=args
    const float* y  = (const float*)d_in[1];
    const float* W1 = (const float*)d_in[2];
    const float* b1 = (const float*)d_in[3];
    const float* W2 = (const float*)d_in[4];
    const float* b2 = (const float*)d_in[5];
    (void)d_ws; (void)ws_size;                 // workspace intentionally untouched

    fused_mlp<<<BB / RS, 256, 0, stream>>>(y, (float*)d_out, W1, b1, W2, b2);
}

// Round 2
// 86.757 us; speedup vs baseline: 1.1391x; 1.1391x over previous
//
#include <hip/hip_runtime.h>

#define BB 16384
#define LL 256
#define HH 16
#define LO (-6.0f)
#define HI (6.0f)
#define NI 256        // intervals
#define NE 257        // entries per latent
#define LT 32         // latents per block tile
#define TPB 512       // threads per block: 8 waves -> 4 blocks/CU = 32 waves/CU (max)
#define SP (TPB / LT) // samples per pass = 16
#define RP 8          // passes; samples per block = SP*RP = 128

static __device__ __forceinline__ float fast_exp2(float x) { return __builtin_amdgcn_exp2f(x); }
static __device__ __forceinline__ float fast_log2(float x) { return __builtin_amdgcn_logf(x); }

// Exact per-latent MLP in base-2 domain (cold fallback for |y| > HI; execz-skipped
// in practice -- N(0,1) inputs essentially never exceed 6 sigma).
static __device__ __forceinline__ float mlp_exact(
    float yv, int l,
    const float* __restrict__ W1, const float* __restrict__ b1,
    const float* __restrict__ W2, const float* __restrict__ b2) {
    const float LOG2E = 1.4426950408889634f;
    float acc2 = b2[l] * LOG2E;
    #pragma unroll 1   // keep cold path compact: minimize register pressure
    for (int h = 0; h < HH; ++h) {
        float x2 = fmaf(yv, W1[l * HH + h] * LOG2E, b1[l * HH + h] * LOG2E);
        float e  = fast_exp2(-fabsf(x2));
        float sp = fmaxf(x2, 0.0f) + fast_log2(1.0f + e);
        acc2 = fmaf(sp, W2[l * HH + h], acc2);
    }
    return __builtin_amdgcn_rcpf(1.0f + fast_exp2(-acc2));
}

// Kernel 1: 4 lanes per LUT entry (4 h-terms each), shfl butterfly reduce.
// 263168 threads = 4128 waves -> ~4 waves/SIMD: hides the trans chain. (~1-2 us)
__global__ __launch_bounds__(256) void build_lut(
    const float* __restrict__ W1, const float* __restrict__ b1,
    const float* __restrict__ W2, const float* __restrict__ b2,
    float* __restrict__ tbl) {
    const float LOG2E = 1.4426950408889634f;
    int gid = blockIdx.x * 256 + threadIdx.x;
    int entry = gid >> 2;                 // (l, i)
    int q = gid & 3;                      // which h-quad
    if (entry >= LL * NE) return;
    int l = entry / NE;
    int i = entry - l * NE;
    float u = LO + (HI - LO) * ((float)i / (float)NI);

    float part = 0.0f;
    #pragma unroll
    for (int hh = 0; hh < 4; ++hh) {
        int h = q * 4 + hh;
        float x2 = fmaf(u, W1[l * HH + h] * LOG2E, b1[l * HH + h] * LOG2E);
        float e  = fast_exp2(-fabsf(x2));
        float sp = fmaxf(x2, 0.0f) + fast_log2(1.0f + e);
        part = fmaf(sp, W2[l * HH + h], part);
    }
    part += __shfl_xor(part, 1, 64);
    part += __shfl_xor(part, 2, 64);      // lanes q=0..3 all hold full sum
    if (q == 0) {
        float acc2 = part + b2[l] * LOG2E;
        tbl[entry] = __builtin_amdgcn_rcpf(1.0f + fast_exp2(-acc2));
    }
}

// Kernel 2: gather + lerp. 512 thr = 32 latents x 16 samples/pass, 8 passes.
// LDS 32.9 KB -> 4 blocks/CU x 8 waves = 32 waves/CU (max occupancy, 2x the
// previous 256-thr config). lt = blockIdx.x & 7 == XCD id under round-robin
// dispatch -> each XCD's L2 holds exactly one 32.9 KB tbl slice.
__global__ __launch_bounds__(TPB, 8) void lut_kernel(
    const float* __restrict__ y, float* __restrict__ out,
    const float* __restrict__ tbl,
    const float* __restrict__ W1, const float* __restrict__ b1,
    const float* __restrict__ W2, const float* __restrict__ b2) {
    __shared__ float s[LT * NE];                // 32.9 KB
    const int lt = blockIdx.x & 7;              // 8 latent tiles
    const int bb = blockIdx.x >> 3;             // 128 sample blocks
    const int l0 = lt * LT;

    const int l_local = threadIdx.x & (LT - 1);
    const int s_idx   = threadIdx.x >> 5;       // 0..15 (sample within pass)
    const int l       = l0 + l_local;

    // Prefetch pass-0 y BEFORE staging: HBM latency hides under stage+barrier.
    int b = bb * (SP * RP) + s_idx;
    float yv = y[b * LL + l];                   // lanes 0..31 read 128 B contiguous

    for (int j = threadIdx.x; j < LT * NE; j += TPB)
        s[j] = tbl[l0 * NE + j];                // coalesced, L2-resident
    __syncthreads();

    const float* __restrict__ srow = s + l_local * NE;  // bank = (l_local+i)%32
    const float SCALE = (float)NI / (HI - LO);

    #pragma unroll
    for (int r = 0; r < RP; ++r) {
        float yn = 0.0f;
        if (r + 1 < RP) yn = y[(b + SP) * LL + l];      // prefetch next pass
        float t = (yv - LO) * SCALE;
        t = fminf(fmaxf(t, 0.0f), (float)NI);
        int i = (int)t;
        i = min(i, NI - 1);
        float fr = t - (float)i;
        float v0 = srow[i];
        float v1 = srow[i + 1];                 // ds_read2_b32 pair
        float res = fmaf(fr, v1 - v0, v0);
        if (__builtin_expect(fabsf(yv) > HI, 0)) {
            res = mlp_exact(yv, l, W1, b1, W2, b2);     // execz-skipped
        }
        out[b * LL + l] = res;                  // coalesced
        yv = yn; b += SP;
    }
}

extern "C" void kernel_launch(void* const* d_in, const int* in_sizes, int n_in,
                              void* d_out, int out_size, void* d_ws, size_t ws_size,
                              hipStream_t stream) {
    // inputs: 0=t, 1=y [B,L], 2=W1 [L,H], 3=b1 [L,H], 4=W2 [L,H], 5=b2 [L], 6=args
    const float* y  = (const float*)d_in[1];
    const float* W1 = (const float*)d_in[2];
    const float* b1 = (const float*)d_in[3];
    const float* W2 = (const float*)d_in[4];
    const float* b2 = (const float*)d_in[5];
    float* out = (float*)d_out;
    float* tbl = (float*)d_ws;                  // 256*257*4 = 263 KB of workspace

    build_lut<<<(LL * NE * 4 + 255) / 256, 256, 0, stream>>>(W1, b1, W2, b2, tbl);
    lut_kernel<<<8 * (BB / (SP * RP)), TPB, 0, stream>>>(y, out, tbl, W1, b1, W2, b2);
}